// Round 1
// baseline (583.490 us; speedup 1.0000x reference)
//
#include <hip/hip_runtime.h>

#define BDIM 8
#define CDIM 256
#define HDIM 96
#define WDIM 96
#define GRP  4
#define CG   64          // channels per group
#define SH   192         // s*H
#define SW   192         // s*W
#define HW   (HDIM*WDIM) // 9216

// ---------------------------------------------------------------------------
// Kernel 1: per-pixel 256->32 dot product (the 1x1 conv offset head).
// One thread per (b,h,w). 32 fp32 accumulators. w_off reads are wave-uniform
// -> compiler emits s_load; unroll-by-4 merges them into s_load_dwordx4.
// Writes offsets pre-scaled by 0.25 into ws, layout [B][32][H][W].
// ---------------------------------------------------------------------------
__global__ __launch_bounds__(256) void dysample_offset_kernel(
    const float* __restrict__ x,
    const float* __restrict__ w_off,
    const float* __restrict__ b_off,
    float* __restrict__ off)
{
    int p  = blockIdx.x * 256 + threadIdx.x;   // [0, B*H*W)
    int b  = p / HW;
    int hw = p - b * HW;

    float acc[32];
    #pragma unroll
    for (int o = 0; o < 32; ++o) acc[o] = b_off[o];

    const float* xp = x + (size_t)b * CDIM * HW + hw;
    #pragma unroll 4
    for (int c = 0; c < CDIM; ++c) {
        float xv = xp[(size_t)c * HW];          // coalesced across lanes
        #pragma unroll
        for (int o = 0; o < 32; ++o)
            acc[o] = fmaf(xv, w_off[o * CDIM + c], acc[o]);
    }

    float* op = off + (size_t)b * 32 * HW + hw;
    #pragma unroll
    for (int o = 0; o < 32; ++o)
        op[(size_t)o * HW] = acc[o] * 0.25f;
}

// ---------------------------------------------------------------------------
// Kernel 2: bilinear sampling. Block = (r, gi, b); 192 threads = output cols.
// Sample point is shared across the group's 64 channels -> compute indices &
// weights once, loop channels with coalesced row stores.
//   h=r>>1, w=cc>>1, offset plane o16 = gi*4 + (r&1)*2 + (cc&1)
//   ix = clip(w + offx, 0, 95); iy = clip(h + offy, 0, 95)
// ---------------------------------------------------------------------------
__global__ __launch_bounds__(192) void dysample_sample_kernel(
    const float* __restrict__ x,
    const float* __restrict__ off,
    float* __restrict__ out)
{
    int cc = threadIdx.x;     // 0..191 output column
    int r  = blockIdx.x;      // 0..191 output row
    int gi = blockIdx.y;      // 0..3
    int b  = blockIdx.z;      // 0..7

    int h  = r >> 1, s1 = r & 1;
    int w  = cc >> 1, s2 = cc & 1;
    int o16 = gi * 4 + s1 * 2 + s2;

    size_t obase = ((size_t)b * 32 + o16) * HW + (size_t)h * WDIM + w;
    float ox = off[obase];
    float oy = off[obase + (size_t)16 * HW];

    float ix = fminf(fmaxf((float)w + ox, 0.0f), (float)(WDIM - 1));
    float iy = fminf(fmaxf((float)h + oy, 0.0f), (float)(HDIM - 1));
    float x0f = floorf(ix), y0f = floorf(iy);
    float wx = ix - x0f,   wy = iy - y0f;
    int x0 = (int)x0f, y0 = (int)y0f;
    int x1 = min(x0 + 1, WDIM - 1);
    int y1 = min(y0 + 1, HDIM - 1);

    float w00 = (1.0f - wy) * (1.0f - wx);
    float w01 = (1.0f - wy) * wx;
    float w10 = wy * (1.0f - wx);
    float w11 = wy * wx;

    int i00 = y0 * WDIM + x0, i01 = y0 * WDIM + x1;
    int i10 = y1 * WDIM + x0, i11 = y1 * WDIM + x1;

    const float* xp = x  + ((size_t)b * CDIM + (size_t)gi * CG) * HW;
    float*       op = out + (((size_t)b * CDIM + (size_t)gi * CG) * SH + r) * SW + cc;

    #pragma unroll 4
    for (int ch = 0; ch < CG; ++ch) {
        const float* p = xp + (size_t)ch * HW;
        float v = p[i00] * w00 + p[i01] * w01 + p[i10] * w10 + p[i11] * w11;
        op[(size_t)ch * (SH * SW)] = v;   // coalesced: lane i -> col i
    }
}

extern "C" void kernel_launch(void* const* d_in, const int* in_sizes, int n_in,
                              void* d_out, int out_size, void* d_ws, size_t ws_size,
                              hipStream_t stream)
{
    const float* x     = (const float*)d_in[0];
    const float* w_off = (const float*)d_in[1];
    const float* b_off = (const float*)d_in[2];
    float* out = (float*)d_out;
    float* off = (float*)d_ws;   // needs 8*32*96*96*4 = 9.44 MB

    // Kernel 1: 73728 pixels / 256 = 288 blocks
    dysample_offset_kernel<<<(BDIM * HW) / 256, 256, 0, stream>>>(x, w_off, b_off, off);

    // Kernel 2: grid (rows, groups, batch), 192 threads = output columns
    dysample_sample_kernel<<<dim3(SH, GRP, BDIM), 192, 0, stream>>>(x, off, out);
}